// Round 1
// baseline (7929.908 us; speedup 1.0000x reference)
//
#include <hip/hip_runtime.h>
#include <math.h>

// ---------------------------------------------------------------------------
// Generic batched strided GEMM (f32):
//   C[z, i, j] = scale * sum_k A[(z%a_mod)*a_batch + i*a_row + k*a_col]
//                         * B[(z/b_div)*b_batch + k*b_row + j*b_col]
//                + bias[(z/b_div)*bias_stride + j]          (if bias != null)
// If k_chunk > 0, z is a K-split chunk index instead: k in [z*k_chunk, min(K, ...)).
// Adaptive load mapping keeps global loads coalesced for both unit-stride-k
// (a_col==1 / b_col==1) and unit-stride-m/n operand layouts.
// ---------------------------------------------------------------------------
template<int BM, int BN, int BK, int TM, int TN>
__global__ __launch_bounds__(256)
void gemm_f32(const float* __restrict__ A, const float* __restrict__ Bm,
              const float* __restrict__ bias, float* __restrict__ C,
              int M, int N, int K,
              long a_batch, long a_row, long a_col, int a_mod,
              long b_batch, long b_row, long b_col, int b_div,
              long bias_stride, long c_batch, long c_row,
              float scale, int k_chunk)
{
    constexpr int NTH = (BM / TM) * (BN / TN);
    static_assert(NTH == 256, "block must be 256 threads");
    const int tid = threadIdx.x;
    const int bz  = blockIdx.z;

    const float* Ab = A + (long)(bz % a_mod) * a_batch;
    const float* Bb = Bm + (long)(bz / b_div) * b_batch;
    float* Cb = C + (long)bz * c_batch;

    const int i0 = blockIdx.y * BM;
    const int j0 = blockIdx.x * BN;

    __shared__ float As[BK][BM + 4];
    __shared__ float Bs[BK][BN + 4];

    int kstart = 0, kend = K;
    if (k_chunk > 0) {
        kstart = bz * k_chunk;
        kend = kstart + k_chunk;
        if (kend > K) kend = K;
    }

    float acc[TM][TN];
#pragma unroll
    for (int x = 0; x < TM; ++x)
#pragma unroll
        for (int y = 0; y < TN; ++y) acc[x][y] = 0.f;

    const int tii = tid / (BN / TN);
    const int tjj = tid % (BN / TN);

    for (int k0 = kstart; k0 < kend; k0 += BK) {
        // ---- stage A tile ----
        if (a_col == 1) {  // k contiguous in memory: 4-wide k chunks per thread
            for (int e = tid * 4; e < BM * BK; e += NTH * 4) {
                int i  = e / BK;
                int kk = e % BK;
                const float* p = Ab + (long)(i0 + i) * a_row + (k0 + kk);
                bool iok = (i0 + i) < M;
#pragma unroll
                for (int u = 0; u < 4; ++u)
                    As[kk + u][i] = (iok && (k0 + kk + u) < kend) ? p[u] : 0.f;
            }
        } else {           // m contiguous (a_row typically 1)
            for (int e = tid * 4; e < BM * BK; e += NTH * 4) {
                int k  = e / BM;
                int ib = e % BM;
                bool kok = (k0 + k) < kend;
                const float* p = Ab + (long)(i0 + ib) * a_row + (long)(k0 + k) * a_col;
#pragma unroll
                for (int u = 0; u < 4; ++u)
                    As[k][ib + u] = (kok && (i0 + ib + u) < M) ? p[(long)u * a_row] : 0.f;
            }
        }
        // ---- stage B tile ----
        if (b_col == 1) {  // n contiguous
            for (int e = tid * 4; e < BN * BK; e += NTH * 4) {
                int k  = e / BN;
                int jb = e % BN;
                bool kok = (k0 + k) < kend;
                const float* p = Bb + (long)(k0 + k) * b_row + (j0 + jb);
#pragma unroll
                for (int u = 0; u < 4; ++u)
                    Bs[k][jb + u] = (kok && (j0 + jb + u) < N) ? p[u] : 0.f;
            }
        } else {           // k contiguous (b_row typically 1)
            for (int e = tid * 4; e < BN * BK; e += NTH * 4) {
                int j  = e / BK;
                int kk = e % BK;
                bool jok = (j0 + j) < N;
                const float* p = Bb + (long)(j0 + j) * b_col + (long)(k0 + kk) * b_row;
#pragma unroll
                for (int u = 0; u < 4; ++u)
                    Bs[kk + u][j] = (jok && (k0 + kk + u) < kend) ? p[(long)u * b_row] : 0.f;
            }
        }
        __syncthreads();
#pragma unroll
        for (int k = 0; k < BK; ++k) {
            float av[TM], bv[TN];
#pragma unroll
            for (int x = 0; x < TM; ++x) av[x] = As[k][tii * TM + x];
#pragma unroll
            for (int y = 0; y < TN; ++y) bv[y] = Bs[k][tjj * TN + y];
#pragma unroll
            for (int x = 0; x < TM; ++x)
#pragma unroll
                for (int y = 0; y < TN; ++y)
                    acc[x][y] = fmaf(av[x], bv[y], acc[x][y]);
        }
        __syncthreads();
    }

    const float* biasp = bias ? (bias + (long)(bz / b_div) * bias_stride) : nullptr;
#pragma unroll
    for (int x = 0; x < TM; ++x) {
        int i = i0 + tii * TM + x;
        if (i >= M) continue;
#pragma unroll
        for (int y = 0; y < TN; ++y) {
            int j = j0 + tjj * TN + y;
            if (j >= N) continue;
            float v = acc[x][y] * scale;
            if (biasp) v += biasp[j];
            Cb[(long)i * c_row + j] = v;
        }
    }
}

// One wave per row, in-place row softmax.
__global__ __launch_bounds__(256)
void softmax_rows(float* __restrict__ S, long nrows, int rowlen)
{
    long row = (long)blockIdx.x * 4 + (threadIdx.x >> 6);
    if (row >= nrows) return;
    int lane = threadIdx.x & 63;
    float* p = S + row * (long)rowlen;
    float m = -3.4e38f;
    for (int c = lane; c < rowlen; c += 64) m = fmaxf(m, p[c]);
#pragma unroll
    for (int off = 32; off > 0; off >>= 1) m = fmaxf(m, __shfl_xor(m, off, 64));
    float s = 0.f;
    for (int c = lane; c < rowlen; c += 64) {
        float e = __expf(p[c] - m);
        p[c] = e;
        s += e;
    }
#pragma unroll
    for (int off = 32; off > 0; off >>= 1) s += __shfl_xor(s, off, 64);
    float inv = 1.f / s;
    for (int c = lane; c < rowlen; c += 64) p[c] *= inv;
}

// dst[i*stride + col_off + j] = bias[j] + sum_z partial[z*rows*cols + i*cols + j]
__global__ __launch_bounds__(256)
void reduce_partials(const float* __restrict__ partial, const float* __restrict__ bias,
                     float* __restrict__ dst, int nz, int rows, int cols,
                     long dst_row_stride, long dst_col_off)
{
    int idx = blockIdx.x * 256 + threadIdx.x;
    if (idx >= rows * cols) return;
    int i = idx / cols, j = idx % cols;
    float s = bias ? bias[j] : 0.f;
    long rc = (long)rows * cols;
    for (int z = 0; z < nz; ++z) s += partial[(long)z * rc + idx];
    dst[(long)i * dst_row_stride + dst_col_off + j] = s;
}

// predicts = h1 @ fnn2_w + fnn2_b  -> out[:, 0:3]  (out row stride 2003)
__global__ __launch_bounds__(256)
void predicts_kernel(const float* __restrict__ h1, const float* __restrict__ w2,
                     const float* __restrict__ b2, float* __restrict__ out)
{
    int idx = threadIdx.x;
    if (idx >= 64 * 3) return;
    int b = idx / 3, c = idx % 3;
    float s = b2[c];
    const float* hr = h1 + (long)b * 768;
    for (int k = 0; k < 768; ++k) s = fmaf(hr[k], w2[k * 3 + c], s);
    out[(long)b * 2003 + c] = s;
}

// ---------------------------------------------------------------------------
static inline void launch_gemm(bool big, hipStream_t s,
    const float* A, const float* Bm, const float* bias, float* C,
    int M, int N, int K,
    long a_batch, long a_row, long a_col, int a_mod,
    long b_batch, long b_row, long b_col, int b_div,
    long bias_stride, long c_batch, long c_row,
    float scale, int batches, int k_chunk)
{
    if (big) {
        dim3 g((N + 127) / 128, (M + 127) / 128, batches);
        gemm_f32<128, 128, 16, 8, 8><<<g, dim3(256), 0, s>>>(
            A, Bm, bias, C, M, N, K, a_batch, a_row, a_col, a_mod,
            b_batch, b_row, b_col, b_div, bias_stride, c_batch, c_row, scale, k_chunk);
    } else {
        dim3 g((N + 63) / 64, (M + 63) / 64, batches);
        gemm_f32<64, 64, 16, 4, 4><<<g, dim3(256), 0, s>>>(
            A, Bm, bias, C, M, N, K, a_batch, a_row, a_col, a_mod,
            b_batch, b_row, b_col, b_div, bias_stride, c_batch, c_row, scale, k_chunk);
    }
}

extern "C" void kernel_launch(void* const* d_in, const int* in_sizes, int n_in,
                              void* d_out, int out_size, void* d_ws, size_t ws_size,
                              hipStream_t stream) {
    if (n_in < 26) return;
    const float* tokens     = (const float*)d_in[0];
    const float* cls_tokens = (const float*)d_in[1];
    const float* a_qkv_w  = (const float*)d_in[2];
    const float* a_qkv_b  = (const float*)d_in[3];
    const float* af_qkv_w = (const float*)d_in[4];
    const float* af_qkv_b = (const float*)d_in[5];
    const float* b_qkv_w  = (const float*)d_in[6];
    const float* b_qkv_b  = (const float*)d_in[7];
    const float* bf_qkv_w = (const float*)d_in[8];
    const float* bf_qkv_b = (const float*)d_in[9];
    const float* atW_w = (const float*)d_in[10];
    const float* atW_b = (const float*)d_in[11];
    const float* afW_w = (const float*)d_in[12];
    const float* afW_b = (const float*)d_in[13];
    const float* btW_w = (const float*)d_in[14];
    const float* btW_b = (const float*)d_in[15];
    const float* bfW_w = (const float*)d_in[16];
    const float* bfW_b = (const float*)d_in[17];
    const float* aft_w = (const float*)d_in[18];
    const float* aft_b = (const float*)d_in[19];
    const float* bft_w = (const float*)d_in[20];
    const float* bft_b = (const float*)d_in[21];
    const float* fnn1_w = (const float*)d_in[22];
    const float* fnn1_b = (const float*)d_in[23];
    const float* fnn2_w = (const float*)d_in[24];
    const float* fnn2_b = (const float*)d_in[25];
    float* outp = (float*)d_out;
    float* ws = (float*)d_ws;

    // ---- workspace layout (floats) ----
    const long CAPQ  = 192L * 272 * 768;   // q|k|v packed region (O aliases q)
    const long TCAPe = 64L * 272 * 100;    // aT / aF
    const long MCAP  = 64L * 100 * 100;    // einsum result
    const long HCAP  = 64L * 768;          // h1
    long ws_floats = (long)(ws_size / 4);
    long fixed = CAPQ + 2 * TCAPe + MCAP + HCAP;
    long s_avail = ws_floats - fixed;
    int NB;            // feature-attention batch chunk (keeps score buf L3-resident)
    long SCAP;
    if (s_avail >= 16L * 589824) { NB = 16; SCAP = 16L * 589824; }
    else                         { NB = 8;  SCAP = 4734976; }   // >= 64*272*272 too

    float* WS0  = ws;
    float* SBUF = WS0 + CAPQ;
    float* TBUF = SBUF + SCAP;
    float* FBUF = TBUF + TCAPe;
    float* MBUF = FBUF + TCAPe;
    float* HBUF = MBUF + MCAP;

    auto phase = [&](int L, const float* tok, long tokRows,
                     const float* qkvW, const float* qkvB,
                     const float* fqkvW, const float* fqkvB,
                     const float* tWw, const float* tWb,
                     const float* fWw, const float* fWb,
                     const float* ftw, const float* ftb, long colOff)
    {
        const long LH = (long)L * 768;
        float* q  = WS0;
        float* kB = WS0 + 64 * LH;
        float* v  = WS0 + 128 * LH;
        float* o  = q;  // O aliases Q (Q dead after scores)

        // 1) token QKV: z = qkv*64 + b; C packed q|k|v
        launch_gemm(true, stream, tok + 768, qkvW, qkvB, WS0,
            L, 768, 768,
            tokRows * 768, 768, 1, 64,
            589824L, 768, 1, 64,
            768, LH, 768, 1.0f, 192, 0);
        // 2) S = q @ k^T * 1/sqrt(H)
        launch_gemm(false, stream, q, kB, nullptr, SBUF,
            L, L, 768,
            LH, 768, 1, 64,
            LH, 1, 768, 1,
            0, (long)L * L, L, 1.0f / sqrtf(768.0f), 64, 0);
        // 3) softmax rows
        { long nr = 64L * L;
          softmax_rows<<<dim3((unsigned)((nr + 3) / 4)), 256, 0, stream>>>(SBUF, nr, L); }
        // 4) aTSA = P @ v  -> o
        launch_gemm(true, stream, SBUF, v, nullptr, o,
            L, 768, L,
            (long)L * L, L, 1, 64,
            LH, 768, 1, 1,
            0, LH, 768, 1.0f, 64, 0);
        // 5) aT = aTSA @ tW + b
        launch_gemm(false, stream, o, tWw, tWb, TBUF,
            L, 100, 768,
            LH, 768, 1, 64,
            0, 100, 1, 1,
            0, (long)L * 100, 100, 1.0f, 64, 0);
        // 6) feature QKV: qf[h,l'] = sum_l x[l,h]*W[l,l'] + b[l']  (overwrites WS0)
        launch_gemm(true, stream, tok + 768, fqkvW, fqkvB, WS0,
            768, L, L,
            tokRows * 768, 1, 768, 64,
            (long)L * L, L, 1, 64,
            L, 768L * L, L, 1.0f, 192, 0);
        // 7) feature attention, NB-batch chunks (S chunk stays L3-resident)
        int nch = 64 / NB;
        for (int c = 0; c < nch; ++c) {
            long co = (long)c * NB * LH;
            launch_gemm(true, stream, q + co, kB + co, nullptr, SBUF,
                768, 768, L,
                LH, L, 1, NB,
                LH, 1, L, 1,
                0, 589824L, 768, 1.0f / sqrtf((float)L), NB, 0);
            { long nr = (long)NB * 768;
              softmax_rows<<<dim3((unsigned)((nr + 3) / 4)), 256, 0, stream>>>(SBUF, nr, 768); }
            // O_pre[h,l] = P @ vf -> o (aliases qf chunk, already consumed)
            launch_gemm(true, stream, SBUF, v + co, nullptr, o + co,
                768, L, 768,
                589824L, 768, 1, NB,
                LH, L, 1, 1,
                0, LH, L, 1.0f, NB, 0);
        }
        // 8) aF[l,n] = sum_h O_pre[h,l] * fW[h,n] + b[n]
        launch_gemm(false, stream, o, fWw, fWb, FBUF,
            L, 100, 768,
            LH, 1, L, 64,
            0, 100, 1, 1,
            0, (long)L * 100, 100, 1.0f, 64, 0);
        // 9) M[m,n] = sum_l aT[l,m] * aF[l,n]
        launch_gemm(false, stream, TBUF, FBUF, nullptr, MBUF,
            100, 100, L,
            (long)L * 100, 1, 100, 64,
            (long)L * 100, 100, 1, 1,
            0, 10000, 100, 1.0f, 64, 0);
        // 10) out = M.reshape(64,10000) @ ft_w : split-K partials (40 x 250)
        launch_gemm(false, stream, MBUF, ftw, nullptr, SBUF,
            64, 1000, 10000,
            0, 10000, 1, 1,
            0, 1000, 1, 1,
            0, 64000, 1000, 1.0f, 40, 250);
        // 11) reduce partials + bias -> d_out[:, colOff:colOff+1000]
        reduce_partials<<<dim3((64 * 1000 + 255) / 256), 256, 0, stream>>>(
            SBUF, ftb, outp, 40, 64, 1000, 2003, colOff);
    };

    // Phase A: L = 272 (LA), phase B: L = 256 (MAXL); pads in reference are no-ops.
    phase(272, tokens,     273, a_qkv_w, a_qkv_b, af_qkv_w, af_qkv_b,
          atW_w, atW_b, afW_w, afW_b, aft_w, aft_b, 3);
    phase(256, cls_tokens, 257, b_qkv_w, b_qkv_b, bf_qkv_w, bf_qkv_b,
          btW_w, btW_b, bfW_w, bfW_b, bft_w, bft_b, 1003);

    // FNN head: h = [CLS | cls_CLS]; h1 = h @ fnn1_w + b1 (split-K over both halves)
    launch_gemm(false, stream, tokens, fnn1_w, nullptr, SBUF,
        64, 768, 768,
        0, 273L * 768, 1, 1,
        0, 768, 1, 1,
        0, 49152, 768, 1.0f, 6, 128);
    launch_gemm(false, stream, cls_tokens, fnn1_w + 768L * 768, nullptr, SBUF + 6L * 49152,
        64, 768, 768,
        0, 257L * 768, 1, 1,
        0, 768, 1, 1,
        0, 49152, 768, 1.0f, 6, 128);
    reduce_partials<<<dim3((64 * 768 + 255) / 256), 256, 0, stream>>>(
        SBUF, fnn1_b, HBUF, 12, 64, 768, 768, 0);
    predicts_kernel<<<dim3(1), 256, 0, stream>>>(HBUF, fnn2_w, fnn2_b, outp);
}

// Round 2
// 1749.417 us; speedup vs baseline: 4.5329x; 4.5329x over previous
//
#include <hip/hip_runtime.h>
#include <hip/hip_bf16.h>
#include <math.h>

typedef __hip_bfloat16 bf16;
typedef __attribute__((ext_vector_type(8))) short bf16x8;
typedef __attribute__((ext_vector_type(4))) float f32x4;

static __device__ __forceinline__ float tofl(float x) { return x; }
static __device__ __forceinline__ float tofl(bf16 x) { return __bfloat162float(x); }

// ---------------------------------------------------------------------------
// Batched MFMA GEMM, both operands K-contiguous ("TN"):
//   C[z,i,j] = scale * sum_k A[(z%a_mod)*a_batch + i*lda + k]
//                      * B[(z/b_div)*b_batch + j*ldb + k]
//              + bias[(z/b_div)*bias_stride + j]
// Requires lda%8==0, ldb%8==0, K%8==0, 16B-aligned base pointers.
// BM=128 fixed, BK=32, 4 waves as 2x2, LDS pitch 40 (2-way max bank conflict).
// ---------------------------------------------------------------------------
template<int BN>
__global__ __launch_bounds__(256)
void gemm_mfma(const bf16* __restrict__ A, const bf16* __restrict__ B,
               const float* __restrict__ bias, void* __restrict__ C, int c_f32,
               int M, int N, int K,
               long a_batch, long lda, int a_mod,
               long b_batch, long ldb, int b_div,
               long bias_stride, long c_batch, long c_row, float scale)
{
    constexpr int BM = 128, PITCH = 40;
    constexpr int WN = BN / 2;
    constexpr int FM = 4, FN = WN / 16;
    constexpr int ACH = (BM * 4) / 256;   // uint4 chunks per thread for A tile
    constexpr int BCH = (BN * 4) / 256;
    __shared__ __align__(16) unsigned short As[BM * PITCH];
    __shared__ __align__(16) unsigned short Bs[BN * PITCH];

    const int tid = threadIdx.x, w = tid >> 6, lane = tid & 63;
    const int wr = w >> 1, wc = w & 1, lrow = lane & 15, lch = lane >> 4;
    const int bz = blockIdx.z;
    const bf16* Ab = A + (long)(bz % a_mod) * a_batch;
    const bf16* Bb = B + (long)(bz / b_div) * b_batch;
    const int i0 = blockIdx.y * BM, j0 = blockIdx.x * BN;

    f32x4 acc[FM][FN];
#pragma unroll
    for (int m = 0; m < FM; ++m)
#pragma unroll
        for (int n = 0; n < FN; ++n) acc[m][n] = (f32x4){0.f, 0.f, 0.f, 0.f};

    const int nt = (K + 31) >> 5;
    uint4 va[ACH], vb[BCH];

    auto loadA = [&](int k0) {
#pragma unroll
        for (int u = 0; u < ACH; ++u) {
            int c = tid + u * 256; int row = c >> 2, col8 = (c & 3) << 3;
            uint4 v; v.x = v.y = v.z = v.w = 0u;
            int gr = i0 + row;
            if (gr < M && k0 + col8 + 8 <= K)
                v = *(const uint4*)(Ab + (long)gr * lda + k0 + col8);
            va[u] = v;
        }
    };
    auto loadB = [&](int k0) {
#pragma unroll
        for (int u = 0; u < BCH; ++u) {
            int c = tid + u * 256; int row = c >> 2, col8 = (c & 3) << 3;
            uint4 v; v.x = v.y = v.z = v.w = 0u;
            int gr = j0 + row;
            if (gr < N && k0 + col8 + 8 <= K)
                v = *(const uint4*)(Bb + (long)gr * ldb + k0 + col8);
            vb[u] = v;
        }
    };

    loadA(0); loadB(0);
    for (int t = 0; t < nt; ++t) {
#pragma unroll
        for (int u = 0; u < ACH; ++u) {
            int c = tid + u * 256; int row = c >> 2, col8 = (c & 3) << 3;
            *(uint4*)&As[row * PITCH + col8] = va[u];
        }
#pragma unroll
        for (int u = 0; u < BCH; ++u) {
            int c = tid + u * 256; int row = c >> 2, col8 = (c & 3) << 3;
            *(uint4*)&Bs[row * PITCH + col8] = vb[u];
        }
        __syncthreads();
        if (t + 1 < nt) { loadA((t + 1) << 5); loadB((t + 1) << 5); }  // prefetch overlaps MFMA
        bf16x8 af[FM], bfv[FN];
#pragma unroll
        for (int m = 0; m < FM; ++m)
            af[m] = *(const bf16x8*)&As[(wr * 64 + m * 16 + lrow) * PITCH + lch * 8];
#pragma unroll
        for (int n = 0; n < FN; ++n)
            bfv[n] = *(const bf16x8*)&Bs[(wc * WN + n * 16 + lrow) * PITCH + lch * 8];
#pragma unroll
        for (int m = 0; m < FM; ++m)
#pragma unroll
            for (int n = 0; n < FN; ++n)
                acc[m][n] = __builtin_amdgcn_mfma_f32_16x16x32_bf16(af[m], bfv[n], acc[m][n], 0, 0, 0);
        __syncthreads();
    }

    const float* bp = bias ? (bias + (long)(bz / b_div) * bias_stride) : nullptr;
#pragma unroll
    for (int n = 0; n < FN; ++n) {
        int cc = j0 + wc * WN + n * 16 + lrow;
        if (cc >= N) continue;
        float bv = bp ? bp[cc] : 0.f;
#pragma unroll
        for (int m = 0; m < FM; ++m) {
            int rbase = i0 + wr * 64 + m * 16 + lch * 4;
#pragma unroll
            for (int j = 0; j < 4; ++j) {
                int r = rbase + j;
                if (r >= M) continue;
                float v = acc[m][n][j] * scale + bv;
                long idx = (long)bz * c_batch + (long)r * c_row + cc;
                if (c_f32) ((float*)C)[idx] = v;
                else       ((bf16*)C)[idx] = __float2bfloat16(v);
            }
        }
    }
}

// Tiled transpose with f32->bf16 or bf16->bf16 convert: dst[z][c][r] = src[z][r][c]
template<typename ST>
__global__ __launch_bounds__(256)
void transpose_to_bf16(const ST* __restrict__ src, bf16* __restrict__ dst,
                       int R, int C, long s_ld, long s_batch, long d_ld, long d_batch)
{
    __shared__ float t[32][33];
    const int z = blockIdx.z;
    const int tx = threadIdx.x & 31, ty = threadIdx.x >> 5;
    const int r0 = blockIdx.y << 5, c0 = blockIdx.x << 5;
    const ST* sb = src + (long)z * s_batch;
#pragma unroll
    for (int i = 0; i < 4; ++i) {
        int r = r0 + ty + i * 8, c = c0 + tx;
        if (r < R && c < C) t[ty + i * 8][tx] = tofl(sb[(long)r * s_ld + c]);
    }
    __syncthreads();
    bf16* db = dst + (long)z * d_batch;
#pragma unroll
    for (int i = 0; i < 4; ++i) {
        int dr = c0 + ty + i * 8, dc = r0 + tx;
        if (dr < C && dc < R) db[(long)dr * d_ld + dc] = __float2bfloat16(t[tx][ty + i * 8]);
    }
}

// dst[b][l][h] (bf16) = src[b*tokRows*768 + (l+1)*768 + h]  (f32)
__global__ __launch_bounds__(256)
void convert_x(const float* __restrict__ src, bf16* __restrict__ dst, int L, int tokRows)
{
    long e = ((long)blockIdx.x * 256 + threadIdx.x) * 4;
    long per = (long)L * 768;
    long b = e / per, rem = e - b * per;
    const float4 v = *(const float4*)(src + b * (long)tokRows * 768 + 768 + rem);
    dst[e + 0] = __float2bfloat16(v.x);
    dst[e + 1] = __float2bfloat16(v.y);
    dst[e + 2] = __float2bfloat16(v.z);
    dst[e + 3] = __float2bfloat16(v.w);
}

// In-place bf16 row softmax (f32 math), one wave per row, rowlen <= 768
__global__ __launch_bounds__(256)
void softmax_rows_bf16(bf16* __restrict__ S, long nrows, int rowlen)
{
    long row = (long)blockIdx.x * 4 + (threadIdx.x >> 6);
    if (row >= nrows) return;
    int lane = threadIdx.x & 63;
    bf16* p = S + row * (long)rowlen;
    float m = -3.4e38f;
    float vals[12];
#pragma unroll
    for (int i = 0; i < 12; ++i) {
        int c = lane + i * 64;
        if (c < rowlen) { vals[i] = __bfloat162float(p[c]); m = fmaxf(m, vals[i]); }
    }
#pragma unroll
    for (int off = 32; off > 0; off >>= 1) m = fmaxf(m, __shfl_xor(m, off, 64));
    float s = 0.f;
#pragma unroll
    for (int i = 0; i < 12; ++i) {
        int c = lane + i * 64;
        if (c < rowlen) { vals[i] = __expf(vals[i] - m); s += vals[i]; }
    }
#pragma unroll
    for (int off = 32; off > 0; off >>= 1) s += __shfl_xor(s, off, 64);
    float inv = 1.f / s;
#pragma unroll
    for (int i = 0; i < 12; ++i) {
        int c = lane + i * 64;
        if (c < rowlen) p[c] = __float2bfloat16(vals[i] * inv);
    }
}

// ---------------------------------------------------------------------------
// f32 GEMM (round-1, kept for tiny tail ops: final 10000-K, FNN)
// ---------------------------------------------------------------------------
template<int BM, int BN, int BK, int TM, int TN>
__global__ __launch_bounds__(256)
void gemm_f32(const float* __restrict__ A, const float* __restrict__ Bm,
              const float* __restrict__ bias, float* __restrict__ C,
              int M, int N, int K,
              long a_batch, long a_row, long a_col, int a_mod,
              long b_batch, long b_row, long b_col, int b_div,
              long bias_stride, long c_batch, long c_row,
              float scale, int k_chunk)
{
    constexpr int NTH = (BM / TM) * (BN / TN);
    const int tid = threadIdx.x;
    const int bz  = blockIdx.z;
    const float* Ab = A + (long)(bz % a_mod) * a_batch;
    const float* Bb = Bm + (long)(bz / b_div) * b_batch;
    float* Cb = C + (long)bz * c_batch;
    const int i0 = blockIdx.y * BM;
    const int j0 = blockIdx.x * BN;
    __shared__ float As[BK][BM + 4];
    __shared__ float Bs[BK][BN + 4];
    int kstart = 0, kend = K;
    if (k_chunk > 0) { kstart = bz * k_chunk; kend = kstart + k_chunk; if (kend > K) kend = K; }
    float acc[TM][TN];
#pragma unroll
    for (int x = 0; x < TM; ++x)
#pragma unroll
        for (int y = 0; y < TN; ++y) acc[x][y] = 0.f;
    const int tii = tid / (BN / TN);
    const int tjj = tid % (BN / TN);
    for (int k0 = kstart; k0 < kend; k0 += BK) {
        if (a_col == 1) {
            for (int e = tid * 4; e < BM * BK; e += NTH * 4) {
                int i = e / BK, kk = e % BK;
                const float* p = Ab + (long)(i0 + i) * a_row + (k0 + kk);
                bool iok = (i0 + i) < M;
#pragma unroll
                for (int u = 0; u < 4; ++u)
                    As[kk + u][i] = (iok && (k0 + kk + u) < kend) ? p[u] : 0.f;
            }
        } else {
            for (int e = tid * 4; e < BM * BK; e += NTH * 4) {
                int k = e / BM, ib = e % BM;
                bool kok = (k0 + k) < kend;
                const float* p = Ab + (long)(i0 + ib) * a_row + (long)(k0 + k) * a_col;
#pragma unroll
                for (int u = 0; u < 4; ++u)
                    As[k][ib + u] = (kok && (i0 + ib + u) < M) ? p[(long)u * a_row] : 0.f;
            }
        }
        if (b_col == 1) {
            for (int e = tid * 4; e < BN * BK; e += NTH * 4) {
                int k = e / BN, jb = e % BN;
                bool kok = (k0 + k) < kend;
                const float* p = Bb + (long)(k0 + k) * b_row + (j0 + jb);
#pragma unroll
                for (int u = 0; u < 4; ++u)
                    Bs[k][jb + u] = (kok && (j0 + jb + u) < N) ? p[u] : 0.f;
            }
        } else {
            for (int e = tid * 4; e < BN * BK; e += NTH * 4) {
                int j = e / BK, kk = e % BK;
                bool jok = (j0 + j) < N;
                const float* p = Bb + (long)(j0 + j) * b_col + (long)(k0 + kk) * b_row;
#pragma unroll
                for (int u = 0; u < 4; ++u)
                    Bs[kk + u][j] = (jok && (k0 + kk + u) < kend) ? p[(long)u * b_row] : 0.f;
            }
        }
        __syncthreads();
#pragma unroll
        for (int k = 0; k < BK; ++k) {
            float av[TM], bv[TN];
#pragma unroll
            for (int x = 0; x < TM; ++x) av[x] = As[k][tii * TM + x];
#pragma unroll
            for (int y = 0; y < TN; ++y) bv[y] = Bs[k][tjj * TN + y];
#pragma unroll
            for (int x = 0; x < TM; ++x)
#pragma unroll
                for (int y = 0; y < TN; ++y)
                    acc[x][y] = fmaf(av[x], bv[y], acc[x][y]);
        }
        __syncthreads();
    }
    const float* biasp = bias ? (bias + (long)(bz / b_div) * bias_stride) : nullptr;
#pragma unroll
    for (int x = 0; x < TM; ++x) {
        int i = i0 + tii * TM + x;
        if (i >= M) continue;
#pragma unroll
        for (int y = 0; y < TN; ++y) {
            int j = j0 + tjj * TN + y;
            if (j >= N) continue;
            float v = acc[x][y] * scale;
            if (biasp) v += biasp[j];
            Cb[(long)i * c_row + j] = v;
        }
    }
}

__global__ __launch_bounds__(256)
void reduce_partials(const float* __restrict__ partial, const float* __restrict__ bias,
                     float* __restrict__ dst, int nz, int rows, int cols,
                     long dst_row_stride, long dst_col_off)
{
    int idx = blockIdx.x * 256 + threadIdx.x;
    if (idx >= rows * cols) return;
    int i = idx / cols, j = idx % cols;
    float s = bias ? bias[j] : 0.f;
    long rc = (long)rows * cols;
    for (int z = 0; z < nz; ++z) s += partial[(long)z * rc + idx];
    dst[(long)i * dst_row_stride + dst_col_off + j] = s;
}

__global__ __launch_bounds__(256)
void predicts_kernel(const float* __restrict__ h1, const float* __restrict__ w2,
                     const float* __restrict__ b2, float* __restrict__ out)
{
    int idx = threadIdx.x;
    if (idx >= 64 * 3) return;
    int b = idx / 3, c = idx % 3;
    float s = b2[c];
    const float* hr = h1 + (long)b * 768;
    for (int k = 0; k < 768; ++k) s = fmaf(hr[k], w2[k * 3 + c], s);
    out[(long)b * 2003 + c] = s;
}

// ---------------------------------------------------------------------------
static inline void launch_gemm_f32(hipStream_t s,
    const float* A, const float* Bm, const float* bias, float* C,
    int M, int N, int K,
    long a_batch, long a_row, long a_col, int a_mod,
    long b_batch, long b_row, long b_col, int b_div,
    long bias_stride, long c_batch, long c_row,
    float scale, int batches, int k_chunk)
{
    dim3 g((N + 63) / 64, (M + 63) / 64, batches);
    gemm_f32<64, 64, 16, 4, 4><<<g, dim3(256), 0, s>>>(
        A, Bm, bias, C, M, N, K, a_batch, a_row, a_col, a_mod,
        b_batch, b_row, b_col, b_div, bias_stride, c_batch, c_row, scale, k_chunk);
}

static inline void mfma_launch(hipStream_t s, int bn,
    const bf16* A, const bf16* B, const float* bias, void* C, int c_f32,
    int M, int N, int K,
    long a_batch, long lda, int a_mod,
    long b_batch, long ldb, int b_div,
    long bias_stride, long c_batch, long c_row, float scale, int nz)
{
    if (bn == 128) {
        dim3 g((N + 127) / 128, (M + 127) / 128, nz);
        gemm_mfma<128><<<g, dim3(256), 0, s>>>(A, B, bias, C, c_f32, M, N, K,
            a_batch, lda, a_mod, b_batch, ldb, b_div, bias_stride, c_batch, c_row, scale);
    } else {
        dim3 g((N + 63) / 64, (M + 127) / 128, nz);
        gemm_mfma<64><<<g, dim3(256), 0, s>>>(A, B, bias, C, c_f32, M, N, K,
            a_batch, lda, a_mod, b_batch, ldb, b_div, bias_stride, c_batch, c_row, scale);
    }
}

extern "C" void kernel_launch(void* const* d_in, const int* in_sizes, int n_in,
                              void* d_out, int out_size, void* d_ws, size_t ws_size,
                              hipStream_t stream) {
    if (n_in < 26) return;
    const float* tokens     = (const float*)d_in[0];
    const float* cls_tokens = (const float*)d_in[1];
    const float* a_qkv_w  = (const float*)d_in[2];
    const float* a_qkv_b  = (const float*)d_in[3];
    const float* af_qkv_w = (const float*)d_in[4];
    const float* af_qkv_b = (const float*)d_in[5];
    const float* b_qkv_w  = (const float*)d_in[6];
    const float* b_qkv_b  = (const float*)d_in[7];
    const float* bf_qkv_w = (const float*)d_in[8];
    const float* bf_qkv_b = (const float*)d_in[9];
    const float* atW_w = (const float*)d_in[10];
    const float* atW_b = (const float*)d_in[11];
    const float* afW_w = (const float*)d_in[12];
    const float* afW_b = (const float*)d_in[13];
    const float* btW_w = (const float*)d_in[14];
    const float* btW_b = (const float*)d_in[15];
    const float* bfW_w = (const float*)d_in[16];
    const float* bfW_b = (const float*)d_in[17];
    const float* aft_w = (const float*)d_in[18];
    const float* aft_b = (const float*)d_in[19];
    const float* bft_w = (const float*)d_in[20];
    const float* bft_b = (const float*)d_in[21];
    const float* fnn1_w = (const float*)d_in[22];
    const float* fnn1_b = (const float*)d_in[23];
    const float* fnn2_w = (const float*)d_in[24];
    const float* fnn2_b = (const float*)d_in[25];
    float* outp = (float*)d_out;
    char* base = (char*)d_ws;

    // ---- workspace byte offsets (sized for L=272; total 193.4 MB) ----
    const size_t OFF_QKV = 0;                 // q|k|v / qf|kf|vf   80,216,064
    const size_t OFF_X   = 80216064;          // xbf -> Vt -> vfT   26,738,688
    const size_t OFF_XT  = 106954752;         // xbfT -> Of         26,738,688
    const size_t OFF_O   = 133693440;         // O -> OfT           26,738,688
    const size_t OFF_SP  = 160432128;         // S/P bf16; aTt/aFt; f32 partials; h1
    const size_t OFF_AT  = 179306496;         // aT bf16 [L][104]
    const size_t OFF_AF  = 182927360;         // aF bf16 [L][104]
    const size_t OFF_M   = 186548224;         // M f32 [64][10000]
    const size_t OFF_W   = 189108224;         // bf16 transposed weights

    auto B16 = [&](size_t off) { return (bf16*)(base + off); };
    auto F32 = [&](size_t off) { return (float*)(base + off); };

    bf16* WqT  = B16(OFF_W);
    bf16* WfT  = WqT + 1769472;
    bf16* atWt = WqT + 1991424;
    bf16* afWt = WqT + 2068224;

    auto phase = [&](int L, const float* tok, int tokRows,
                     const float* qkvW, const float* qkvB,
                     const float* fqkvW, const float* fqkvB,
                     const float* tWw, const float* tWb,
                     const float* fWw, const float* fWb,
                     const float* ftw, const float* ftb, long colOff)
    {
        const long LH = (long)L * 768;
        const long LL = (long)L * L;
        bf16* qkv = B16(OFF_QKV);
        bf16* q = qkv, *k = qkv + 64 * LH, *v = qkv + 128 * LH;
        bf16* xbf = B16(OFF_X);   bf16* Vt = xbf; bf16* vfT = xbf;
        bf16* xbT = B16(OFF_XT);  bf16* Of = xbT;
        bf16* O   = B16(OFF_O);   bf16* OfT = O;
        bf16* SP  = B16(OFF_SP);
        bf16* aT  = B16(OFF_AT);
        bf16* aF  = B16(OFF_AF);
        bf16* aTt = B16(OFF_SP);
        bf16* aFt = B16(OFF_SP + 3481600);
        float* Mf   = F32(OFF_M);
        float* PART = F32(OFF_SP + 8000000);
        const int Lg = (L + 31) / 32;
        const float rsH = 1.0f / sqrtf(768.0f);
        const float rsL = 1.0f / sqrtf((float)L);

        // converts / weight transposes
        convert_x<<<dim3((unsigned)(64L * L * 768 / 1024)), 256, 0, stream>>>(tok, xbf, L, tokRows);
        transpose_to_bf16<bf16><<<dim3(24, Lg, 64), 256, 0, stream>>>(xbf, xbT, L, 768, 768, LH, L, LH);
        transpose_to_bf16<float><<<dim3(24, 24, 3), 256, 0, stream>>>(qkvW, WqT, 768, 768, 768, 589824, 768, 589824);
        transpose_to_bf16<float><<<dim3(Lg, Lg, 3), 256, 0, stream>>>(fqkvW, WfT, L, L, L, LL, L, LL);
        transpose_to_bf16<float><<<dim3(4, 24, 1), 256, 0, stream>>>(tWw, atWt, 768, 100, 100, 0, 768, 0);
        transpose_to_bf16<float><<<dim3(4, 24, 1), 256, 0, stream>>>(fWw, afWt, 768, 100, 100, 0, 768, 0);

        // token branch
        mfma_launch(stream, 128, xbf, WqT, qkvB, qkv, 0, L, 768, 768,
                    LH, 768, 64, 589824, 768, 64, 768, LH, 768, 1.0f, 192);
        transpose_to_bf16<bf16><<<dim3(24, Lg, 64), 256, 0, stream>>>(v, Vt, L, 768, 768, LH, L, LH);
        mfma_launch(stream, 128, q, k, nullptr, SP, 0, L, L, 768,
                    LH, 768, 64, LH, 768, 1, 0, LL, L, rsH, 64);
        softmax_rows_bf16<<<dim3((unsigned)((64L * L + 3) / 4)), 256, 0, stream>>>(SP, 64L * L, L);
        mfma_launch(stream, 128, SP, Vt, nullptr, O, 0, L, 768, L,
                    LL, L, 64, LH, L, 1, 0, LH, 768, 1.0f, 64);
        mfma_launch(stream, 64, O, atWt, tWb, aT, 0, L, 100, 768,
                    LH, 768, 64, 0, 768, 1, 0, (long)L * 104, 104, 1.0f, 64);

        // feature branch
        mfma_launch(stream, 128, xbT, WfT, fqkvB, qkv, 0, 768, L, L,
                    LH, L, 64, LL, L, 64, L, LH, L, 1.0f, 192);
        transpose_to_bf16<bf16><<<dim3(Lg, 24, 64), 256, 0, stream>>>(v, vfT, 768, L, L, LH, 768, LH);
        for (int c = 0; c < 4; ++c) {   // 16-batch chunks
            long co = (long)c * 16 * LH;
            mfma_launch(stream, 128, q + co, k + co, nullptr, SP, 0, 768, 768, L,
                        LH, L, 16, LH, L, 1, 0, 589824, 768, rsL, 16);
            softmax_rows_bf16<<<dim3(16 * 768 / 4), 256, 0, stream>>>(SP, 16L * 768, 768);
            mfma_launch(stream, 128, SP, vfT + co, nullptr, Of + co, 0, 768, L, 768,
                        589824, 768, 16, LH, 768, 1, 0, LH, L, 1.0f, 16);
        }
        transpose_to_bf16<bf16><<<dim3(Lg, 24, 64), 256, 0, stream>>>(Of, OfT, 768, L, L, LH, 768, LH);
        mfma_launch(stream, 64, OfT, afWt, fWb, aF, 0, L, 100, 768,
                    LH, 768, 64, 0, 768, 1, 0, (long)L * 104, 104, 1.0f, 64);

        // einsum + final projection
        transpose_to_bf16<bf16><<<dim3(4, Lg, 64), 256, 0, stream>>>(aT, aTt, L, 100, 104, (long)L * 104, L, (long)100 * L);
        transpose_to_bf16<bf16><<<dim3(4, Lg, 64), 256, 0, stream>>>(aF, aFt, L, 100, 104, (long)L * 104, L, (long)100 * L);
        mfma_launch(stream, 128, aTt, aFt, nullptr, Mf, 1, 100, 100, L,
                    (long)100 * L, L, 64, (long)100 * L, L, 1, 0, 10000, 100, 1.0f, 64);
        launch_gemm_f32(stream, Mf, ftw, nullptr, PART, 64, 1000, 10000,
                        0, 10000, 1, 1, 0, 1000, 1, 1, 0, 64000, 1000, 1.0f, 25, 400);
        reduce_partials<<<dim3((64 * 1000 + 255) / 256), 256, 0, stream>>>(
            PART, ftb, outp, 25, 64, 1000, 2003, colOff);
    };

    phase(272, tokens,     273, a_qkv_w, a_qkv_b, af_qkv_w, af_qkv_b,
          atW_w, atW_b, afW_w, afW_b, aft_w, aft_b, 3);
    phase(256, cls_tokens, 257, b_qkv_w, b_qkv_b, bf_qkv_w, bf_qkv_b,
          btW_w, btW_b, bfW_w, bfW_b, bft_w, bft_b, 1003);

    // FNN head (f32): h = [CLS | cls_CLS]; split-K over the two halves
    float* PARTF = F32(OFF_SP);
    float* h1    = F32(OFF_SP + 4000000);
    launch_gemm_f32(stream, tokens, fnn1_w, nullptr, PARTF, 64, 768, 768,
                    0, 273L * 768, 1, 1, 0, 768, 1, 1, 0, 49152, 768, 1.0f, 6, 128);
    launch_gemm_f32(stream, cls_tokens, fnn1_w + 768L * 768, nullptr, PARTF + 6L * 49152, 64, 768, 768,
                    0, 257L * 768, 1, 1, 0, 768, 1, 1, 0, 49152, 768, 1.0f, 6, 128);
    reduce_partials<<<dim3((64 * 768 + 255) / 256), 256, 0, stream>>>(
        PARTF, fnn1_b, h1, 12, 64, 768, 768, 0);
    predicts_kernel<<<dim3(1), 256, 0, stream>>>(h1, fnn2_w, fnn2_b, outp);
}